// Round 1
// baseline (645.589 us; speedup 1.0000x reference)
//
#include <hip/hip_runtime.h>
#include <hip/hip_bf16.h>

typedef unsigned short u16;
typedef __attribute__((ext_vector_type(8))) __bf16 bf16x8;
typedef __attribute__((ext_vector_type(8))) short  s16x8;
typedef __attribute__((ext_vector_type(4))) short  s16x4;
typedef __attribute__((ext_vector_type(4))) float  f32x4;

#define NB 65536
// ws byte offsets
#define OFF_GRAD   0u
#define OFF_SUMSQ  1048576u
#define OFF_CONSTS 1310720u
#define OFF_WF1T   1327104u
#define OFF_WG2T   2375680u
#define OFF_WFPT   2637824u
#define OFF_ET     3162112u
#define OFF_AFF    3194880u
#define OFF_GATED  7389184u
#define WS_NEEDED  74498048u
// consts float indices
#define CI_SRC   0
#define CI_TGT   1024
#define CI_C0    2048
#define CI_INVE  2304
#define CI_ABIAS 2336

__device__ inline float bf2f(u16 u) { union { unsigned int i; float f; } v; v.i = ((unsigned int)u) << 16; return v.f; }
__device__ inline u16 f2bf(float f) { union { float f; unsigned int i; } v; v.f = f; return (u16)((v.i + 0x7fffu + ((v.i >> 16) & 1u)) >> 16); }
// tanh-approx gelu, max abs err ~3e-4 (threshold is 5.4e-2)
__device__ inline float gelu(float x) {
  float z = 1.5957691216f * x * (1.0f + 0.044715f * x * x);
  return x * __builtin_amdgcn_rcpf(1.0f + __expf(-z));
}
__device__ inline float sigm(float x) { return __builtin_amdgcn_rcpf(1.0f + __expf(-x)); }

// async global->LDS, 16B per lane. LDS dest = wave-uniform base + lane*16.
typedef __attribute__((address_space(3))) unsigned int as3_u32;
typedef __attribute__((address_space(1))) unsigned int as1_u32;
__device__ __forceinline__ void gload16(const u16* g, u16* l) {
  __builtin_amdgcn_global_load_lds((const as1_u32*)g, (as3_u32*)l, 16, 0, 0);
}

// ---------------- feat f32 -> bf16 (one-time, memory-bound) ----------------
__global__ __launch_bounds__(256) void k_cvt(const float* __restrict__ feat, u16* __restrict__ featbf) {
  int idx = (blockIdx.x << 8) + threadIdx.x;   // 8 elems/thread
  const float4* src = (const float4*)feat + (idx << 1);
  float4 v0 = src[0], v1 = src[1];
  s16x8 o;
  o[0] = (short)f2bf(v0.x); o[1] = (short)f2bf(v0.y);
  o[2] = (short)f2bf(v0.z); o[3] = (short)f2bf(v0.w);
  o[4] = (short)f2bf(v1.x); o[5] = (short)f2bf(v1.y);
  o[6] = (short)f2bf(v1.z); o[7] = (short)f2bf(v1.w);
  *(s16x8*)(featbf + (idx << 3)) = o;
}

// ---------------- precompute (batch-independent constants) ----------------
__global__ __launch_bounds__(256) void k_pre(
    const float* __restrict__ sfp, const float* __restrict__ tfp,
    const float* __restrict__ wf1, const float* __restrict__ bf1,
    const float* __restrict__ wc,  const float* __restrict__ bc,
    const float* __restrict__ wg1, const float* __restrict__ bg1,
    const float* __restrict__ wfq, const float* __restrict__ bfq,
    const float* __restrict__ E,   float* __restrict__ consts)
{
  __shared__ float s_s[64], s_t[64], s_c[4], s_fp[512];
  const int t = threadIdx.x;
  const int b = blockIdx.x;
  if (t < 64) { s_s[t] = sfp[t]; s_t[t] = tfp[t]; }
  __syncthreads();
  if (b < 8) {
    if (t < 128) {
      int n = b * 128 + t;
      int f = n >> 8, h = n & 255;
      float as = bf1[f * 256 + h];
      float at = as;
      const float* col = wf1 + f * 147456 + 512 * 256 + h;  // wf1[f][512+j][h]
      #pragma unroll 8
      for (int j = 0; j < 64; ++j) {
        float wv = col[j * 256];
        as += s_s[j] * wv; at += s_t[j] * wv;
      }
      consts[CI_SRC + n] = as;
      consts[CI_TGT + n] = at;
    }
  } else if (b == 8) {
    if (t < 4) {
      float a = bc[t];
      for (int j = 0; j < 64; ++j)
        a += s_s[j] * wc[j * 4 + t] + s_t[j] * wc[(64 + j) * 4 + t];
      s_c[t] = tanhf(a);
    }
    __syncthreads();
    float a = bg1[t];
    #pragma unroll
    for (int f = 0; f < 4; ++f) a += s_c[f] * wg1[(4 + f) * 256 + t];
    for (int j = 0; j < 64; ++j) a += s_s[j] * wg1[(8 + j) * 256 + t];
    consts[CI_C0 + t] = a;
  } else {
    for (int d = t; d < 512; d += 256) {
      float a = bfq[d];
      for (int j = 0; j < 64; ++j) a += s_s[j] * wfq[j * 512 + d];
      s_fp[d] = a;
    }
    __syncthreads();
    if (t < 32) {
      float ss = 0.f, dot = 0.f;
      for (int d = 0; d < 512; ++d) {
        float e = E[t * 512 + d];
        ss += e * e; dot += e * s_fp[d];
      }
      float inv = 1.0f / fmaxf(sqrtf(ss), 1e-12f);
      consts[CI_INVE + t] = inv;
      consts[CI_ABIAS + t] = 0.3f * inv * dot;
    }
  }
}

// ---------------- f32 weights -> bf16 transposed [N][K] for MFMA B-frags ----------------
__global__ __launch_bounds__(256) void k_transpose(
    const float* __restrict__ wf1, const float* __restrict__ wg2,
    const float* __restrict__ wfp, const float* __restrict__ E,
    u16* __restrict__ ws16)
{
  int tile = blockIdx.x;
  const float* src; u16* dst; int K, N, tl;
  if (tile < 512)      { int f = tile >> 7; tl = tile & 127; src = wf1 + f * 147456; dst = ws16 + (OFF_WF1T >> 1) + f * 131072; K = 512; N = 256; }
  else if (tile < 640) { tl = tile - 512; src = wg2; dst = ws16 + (OFF_WG2T >> 1); K = 256; N = 512; }
  else if (tile < 896) { tl = tile - 640; src = wfp; dst = ws16 + (OFF_WFPT >> 1); K = 512; N = 512; }
  else                 { tl = tile - 896; src = E;   dst = ws16 + (OFF_ET   >> 1); K = 32;  N = 512; }
  int ntn = N >> 5;
  int r0 = (tl / ntn) << 5, c0 = (tl % ntn) << 5;
  __shared__ float T[32][33];
  const int t = threadIdx.x;
  {
    int r = t >> 3, c4 = (t & 7) << 2;
    float4 v = *(const float4*)(src + (r0 + r) * N + c0 + c4);
    T[r][c4] = v.x; T[r][c4 + 1] = v.y; T[r][c4 + 2] = v.z; T[r][c4 + 3] = v.w;
  }
  __syncthreads();
  {
    int c = t >> 3, r4 = (t & 7) << 2;
    s16x4 v;
    v[0] = (short)f2bf(T[r4 + 0][c]); v[1] = (short)f2bf(T[r4 + 1][c]);
    v[2] = (short)f2bf(T[r4 + 2][c]); v[3] = (short)f2bf(T[r4 + 3][c]);
    *(s16x4*)(dst + (c0 + c) * K + r0 + r4) = v;
  }
}

// ---------------- potential GEMM + gelu-difference reduction -> gradient ----------------
__global__ __launch_bounds__(256, 2) void k_potential(
    const u16* __restrict__ featbf, const u16* __restrict__ wf1t,
    const float* __restrict__ wf2,  const float* __restrict__ consts,
    float* __restrict__ grad)
{
  __shared__ u16 Al[128][32];   // linear: global_load_lds dest
  __shared__ u16 Bl[256][32];
  const int col0 = blockIdx.x << 8;     // f-block: 256 cols
  const int row0 = blockIdx.y << 7;
  const int f = blockIdx.x;
  const int t = threadIdx.x;
  const int w = t >> 6, lane = t & 63, lr = lane & 15, lq = lane >> 4;
  const int gr = lane >> 2, gc = (lane & 3) << 3;  // staging coords (16B/lane)

  f32x4 acc[2][16];
  #pragma unroll
  for (int i = 0; i < 2; ++i)
    #pragma unroll
    for (int j = 0; j < 16; ++j) { f32x4 z = {0.f, 0.f, 0.f, 0.f}; acc[i][j] = z; }

  for (int k0 = 0; k0 < 512; k0 += 32) {
    __syncthreads();
    // A: featbf 128x32 direct-to-LDS
    #pragma unroll
    for (int j = 0; j < 2; ++j) {
      int rb = (j << 6) + (w << 4);
      gload16(featbf + (row0 + rb + gr) * 512 + k0 + gc, &Al[rb][0]);
    }
    // B: wf1t 256x32 direct-to-LDS
    #pragma unroll
    for (int j = 0; j < 4; ++j) {
      int rb = (j << 6) + (w << 4);
      gload16(wf1t + (col0 + rb + gr) * 512 + k0 + gc, &Bl[rb][0]);
    }
    __syncthreads();
    bf16x8 a[2];
    #pragma unroll
    for (int rt = 0; rt < 2; ++rt)
      a[rt] = *(const bf16x8*)&Al[(w << 5) + (rt << 4) + lr][lq << 3];
    #pragma unroll
    for (int ct = 0; ct < 16; ++ct) {
      bf16x8 bb = *(const bf16x8*)&Bl[(ct << 4) + lr][lq << 3];
      acc[0][ct] = __builtin_amdgcn_mfma_f32_16x16x32_bf16(a[0], bb, acc[0][ct], 0, 0, 0);
      acc[1][ct] = __builtin_amdgcn_mfma_f32_16x16x32_bf16(a[1], bb, acc[1][ct], 0, 0, 0);
    }
  }
  float part[2][4] = {{0, 0, 0, 0}, {0, 0, 0, 0}};
  #pragma unroll
  for (int ct = 0; ct < 16; ++ct) {
    int n = col0 + (ct << 4) + lr;
    float so = consts[CI_SRC + n];
    float to = consts[CI_TGT + n];
    float w2 = wf2[n];
    #pragma unroll
    for (int rt = 0; rt < 2; ++rt)
      #pragma unroll
      for (int j = 0; j < 4; ++j) {
        float c = acc[rt][ct][j];
        part[rt][j] += (gelu(c + to) - gelu(c + so)) * w2;
      }
  }
  #pragma unroll
  for (int m = 1; m <= 8; m <<= 1)
    #pragma unroll
    for (int rt = 0; rt < 2; ++rt)
      #pragma unroll
      for (int j = 0; j < 4; ++j)
        part[rt][j] += __shfl_xor(part[rt][j], m, 64);
  if (lr == 0) {
    #pragma unroll
    for (int rt = 0; rt < 2; ++rt)
      #pragma unroll
      for (int j = 0; j < 4; ++j) {
        int r = row0 + (w << 5) + (rt << 4) + (lq << 2) + j;
        grad[r * 4 + f] = part[rt][j];
      }
  }
}

// ---------------- gate MLP + gated = features * gate ----------------
__global__ __launch_bounds__(256, 2) void k_gate(
    const u16* __restrict__ featbf, const float* __restrict__ grad,
    const float* __restrict__ wg1,  const u16* __restrict__ wg2t,
    const float* __restrict__ bg2,  const float* __restrict__ consts,
    u16* __restrict__ gated)
{
  __shared__ u16 Hl[128][264];   // hg bf16 (A), later reused as gate tile [128][136]
  __shared__ u16 Bl[128][32];    // linear: global_load_lds dest
  const int col0 = blockIdx.x << 7;
  const int row0 = blockIdx.y << 7;
  const int t = threadIdx.x;
  const int w = t >> 6, lane = t & 63, lr = lane & 15, lq = lane >> 4;
  const int gr = lane >> 2, gc = (lane & 3) << 3;

  // phase 1: hg[r][h] = gelu(c0[h] + grad[r]·Wg1[0:4,h]), h = t
  {
    float wv[4], c0v = consts[CI_C0 + t];
    #pragma unroll
    for (int f = 0; f < 4; ++f) wv[f] = wg1[f * 256 + t];
    for (int i = 0; i < 128; ++i) {
      float4 g = *(const float4*)(grad + ((row0 + i) << 2));
      float p = c0v + g.x * wv[0] + g.y * wv[1] + g.z * wv[2] + g.w * wv[3];
      Hl[i][t] = f2bf(gelu(p));
    }
  }
  f32x4 acc[2][8];
  #pragma unroll
  for (int i = 0; i < 2; ++i)
    #pragma unroll
    for (int j = 0; j < 8; ++j) { f32x4 z = {0.f, 0.f, 0.f, 0.f}; acc[i][j] = z; }

  for (int k0 = 0; k0 < 256; k0 += 32) {
    __syncthreads();
    #pragma unroll
    for (int j = 0; j < 2; ++j) {
      int rb = (j << 6) + (w << 4);
      gload16(wg2t + (col0 + rb + gr) * 256 + k0 + gc, &Bl[rb][0]);
    }
    __syncthreads();
    bf16x8 a[2];
    #pragma unroll
    for (int rt = 0; rt < 2; ++rt)
      a[rt] = *(const bf16x8*)&Hl[(w << 5) + (rt << 4) + lr][k0 + (lq << 3)];
    #pragma unroll
    for (int ct = 0; ct < 8; ++ct) {
      bf16x8 bb = *(const bf16x8*)&Bl[(ct << 4) + lr][lq << 3];
      acc[0][ct] = __builtin_amdgcn_mfma_f32_16x16x32_bf16(a[0], bb, acc[0][ct], 0, 0, 0);
      acc[1][ct] = __builtin_amdgcn_mfma_f32_16x16x32_bf16(a[1], bb, acc[1][ct], 0, 0, 0);
    }
  }
  __syncthreads();
  u16* Gl = &Hl[0][0];                  // gate tile [128][136]
  #pragma unroll
  for (int ct = 0; ct < 8; ++ct) {
    int n = col0 + (ct << 4) + lr;
    float bv = bg2[n];
    #pragma unroll
    for (int rt = 0; rt < 2; ++rt)
      #pragma unroll
      for (int j = 0; j < 4; ++j) {
        int r = (w << 5) + (rt << 4) + (lq << 2) + j;
        Gl[r * 136 + (ct << 4) + lr] = f2bf(sigm(acc[rt][ct][j] + bv));
      }
  }
  __syncthreads();
  #pragma unroll
  for (int it = 0; it < 8; ++it) {
    int s = (it << 8) + t;
    int r = s >> 4, c8 = (s & 15) << 3;
    s16x8 f8 = *(const s16x8*)(featbf + (row0 + r) * 512 + col0 + c8);
    s16x8 g8 = *(const s16x8*)(Gl + r * 136 + c8);
    s16x8 o;
    #pragma unroll
    for (int j = 0; j < 8; ++j)
      o[j] = (short)f2bf(bf2f((u16)f8[j]) * bf2f((u16)g8[j]));
    *(s16x8*)(gated + (row0 + r) * 512 + col0 + c8) = o;
  }
}

// ---------------- y = gated @ Wfp + bfp; row sum-of-squares; y -> d_out (scratch) ----------------
__global__ __launch_bounds__(256, 2) void k_proj(
    const u16* __restrict__ gated, const u16* __restrict__ wfpt,
    const float* __restrict__ bfp, u16* __restrict__ y,
    float* __restrict__ sumsq)
{
  __shared__ u16 U[128 * 264];
  u16 (*Al)[32] = (u16(*)[32])U;             // 128x32 linear
  u16 (*Bl)[32] = (u16(*)[32])(U + 4096);    // 256x32 linear
  const int col0 = blockIdx.x << 8;
  const int row0 = blockIdx.y << 7;
  const int t = threadIdx.x;
  const int w = t >> 6, lane = t & 63, lr = lane & 15, lq = lane >> 4;
  const int gr = lane >> 2, gc = (lane & 3) << 3;

  f32x4 acc[2][16];
  #pragma unroll
  for (int i = 0; i < 2; ++i)
    #pragma unroll
    for (int j = 0; j < 16; ++j) { f32x4 z = {0.f, 0.f, 0.f, 0.f}; acc[i][j] = z; }

  for (int k0 = 0; k0 < 512; k0 += 32) {
    __syncthreads();
    #pragma unroll
    for (int j = 0; j < 2; ++j) {
      int rb = (j << 6) + (w << 4);
      gload16(gated + (row0 + rb + gr) * 512 + k0 + gc, &Al[rb][0]);
    }
    #pragma unroll
    for (int j = 0; j < 4; ++j) {
      int rb = (j << 6) + (w << 4);
      gload16(wfpt + (col0 + rb + gr) * 512 + k0 + gc, &Bl[rb][0]);
    }
    __syncthreads();
    bf16x8 a[2];
    #pragma unroll
    for (int rt = 0; rt < 2; ++rt)
      a[rt] = *(const bf16x8*)&Al[(w << 5) + (rt << 4) + lr][lq << 3];
    #pragma unroll
    for (int ct = 0; ct < 16; ++ct) {
      bf16x8 bb = *(const bf16x8*)&Bl[(ct << 4) + lr][lq << 3];
      acc[0][ct] = __builtin_amdgcn_mfma_f32_16x16x32_bf16(a[0], bb, acc[0][ct], 0, 0, 0);
      acc[1][ct] = __builtin_amdgcn_mfma_f32_16x16x32_bf16(a[1], bb, acc[1][ct], 0, 0, 0);
    }
  }
  float part[2][4] = {{0, 0, 0, 0}, {0, 0, 0, 0}};
  #pragma unroll
  for (int ct = 0; ct < 16; ++ct) {
    float bv = bfp[col0 + (ct << 4) + lr];
    #pragma unroll
    for (int rt = 0; rt < 2; ++rt)
      #pragma unroll
      for (int j = 0; j < 4; ++j) {
        acc[rt][ct][j] += bv;
        part[rt][j] += acc[rt][ct][j] * acc[rt][ct][j];
      }
  }
  #pragma unroll
  for (int m = 1; m <= 8; m <<= 1)
    #pragma unroll
    for (int rt = 0; rt < 2; ++rt)
      #pragma unroll
      for (int j = 0; j < 4; ++j)
        part[rt][j] += __shfl_xor(part[rt][j], m, 64);
  if (lr == 0) {
    #pragma unroll
    for (int rt = 0; rt < 2; ++rt)
      #pragma unroll
      for (int j = 0; j < 4; ++j)
        atomicAdd(&sumsq[row0 + (w << 5) + (rt << 4) + (lq << 2) + j], part[rt][j]);
  }
  __syncthreads();
  u16* Yl = U;                          // bounce [128][264]
  #pragma unroll
  for (int ct = 0; ct < 16; ++ct)
    #pragma unroll
    for (int rt = 0; rt < 2; ++rt)
      #pragma unroll
      for (int j = 0; j < 4; ++j) {
        int r = (w << 5) + (rt << 4) + (lq << 2) + j;
        Yl[r * 264 + (ct << 4) + lr] = f2bf(acc[rt][ct][j]);
      }
  __syncthreads();
  #pragma unroll
  for (int it = 0; it < 16; ++it) {
    int s = (it << 8) + t;
    int r = s >> 5, c8 = (s & 31) << 3;
    *(s16x8*)(y + (row0 + r) * 512 + col0 + c8) = *(const s16x8*)(Yl + r * 264 + c8);
  }
}

// ---------------- aff = softmax(normalize(y) @ anchors_norm^T + abias) ----------------
__global__ __launch_bounds__(256, 2) void k_aff(
    const u16* __restrict__ y, const float* __restrict__ E,
    const float* __restrict__ sumsq, const float* __restrict__ consts,
    u16* __restrict__ aff)
{
  __shared__ u16 El[32][520];
  __shared__ u16 Al[256][32];   // linear: global_load_lds dest
  const int row0 = blockIdx.x << 8;
  const int t = threadIdx.x;
  const int w = t >> 6, lane = t & 63, lr = lane & 15, lq = lane >> 4;
  const int gr = lane >> 2, gc = (lane & 3) << 3;
  #pragma unroll
  for (int i = 0; i < 16; ++i) {
    int s = (i << 8) + t;
    int a = s >> 7, c4 = (s & 127) << 2;
    float4 v = *(const float4*)(E + a * 512 + c4);
    s16x4 b;
    b[0] = (short)f2bf(v.x); b[1] = (short)f2bf(v.y);
    b[2] = (short)f2bf(v.z); b[3] = (short)f2bf(v.w);
    *(s16x4*)&El[a][c4] = b;
  }
  f32x4 acc[4][2];
  #pragma unroll
  for (int i = 0; i < 4; ++i)
    #pragma unroll
    for (int j = 0; j < 2; ++j) { f32x4 z = {0.f, 0.f, 0.f, 0.f}; acc[i][j] = z; }

  for (int k0 = 0; k0 < 512; k0 += 32) {
    __syncthreads();
    #pragma unroll
    for (int j = 0; j < 4; ++j) {
      int rb = (j << 6) + (w << 4);
      gload16(y + (row0 + rb + gr) * 512 + k0 + gc, &Al[rb][0]);
    }
    __syncthreads();
    bf16x8 b0 = *(const bf16x8*)&El[lr][k0 + (lq << 3)];
    bf16x8 b1 = *(const bf16x8*)&El[16 + lr][k0 + (lq << 3)];
    #pragma unroll
    for (int rt = 0; rt < 4; ++rt) {
      bf16x8 a = *(const bf16x8*)&Al[(w << 6) + (rt << 4) + lr][lq << 3];
      acc[rt][0] = __builtin_amdgcn_mfma_f32_16x16x32_bf16(a, b0, acc[rt][0], 0, 0, 0);
      acc[rt][1] = __builtin_amdgcn_mfma_f32_16x16x32_bf16(a, b1, acc[rt][1], 0, 0, 0);
    }
  }
  float iv0 = consts[CI_INVE + lr],  iv1 = consts[CI_INVE + 16 + lr];
  float ab0 = consts[CI_ABIAS + lr], ab1 = consts[CI_ABIAS + 16 + lr];
  #pragma unroll
  for (int rt = 0; rt < 4; ++rt) {
    #pragma unroll
    for (int j = 0; j < 4; ++j) {
      int r = row0 + (w << 6) + (rt << 4) + (lq << 2) + j;
      float invn = 1.0f / fmaxf(sqrtf(sumsq[r]), 1e-12f);
      float v0 = acc[rt][0][j] * iv0 * invn + ab0;
      float v1 = acc[rt][1][j] * iv1 * invn + ab1;
      float mx = fmaxf(v0, v1);
      #pragma unroll
      for (int m = 1; m <= 8; m <<= 1) mx = fmaxf(mx, __shfl_xor(mx, m, 64));
      float e0 = __expf(v0 - mx), e1 = __expf(v1 - mx);
      float sm = e0 + e1;
      #pragma unroll
      for (int m = 1; m <= 8; m <<= 1) sm += __shfl_xor(sm, m, 64);
      float rs = 1.0f / sm;
      aff[r * 32 + lr]      = f2bf(e0 * rs);
      aff[r * 32 + 16 + lr] = f2bf(e1 * rs);
    }
  }
}

// ---------------- out = gated + aff @ E  (f32 output!) ----------------
__global__ __launch_bounds__(256, 2) void k_out(
    const u16* __restrict__ gated, const u16* __restrict__ aff,
    const u16* __restrict__ et, float* __restrict__ out)
{
  __shared__ u16 ETl[512][40];
  __shared__ u16 Afl[64][40];
  __shared__ u16 Ol[64][520];
  const int row0 = blockIdx.x << 6;
  const int t = threadIdx.x;
  const int w = t >> 6, lane = t & 63, lr = lane & 15, lq = lane >> 4;
  {
    int r = t >> 2, k8 = (t & 3) << 3;
    *(bf16x8*)&Afl[r][k8] = *(const bf16x8*)(aff + (row0 + r) * 32 + k8);
  }
  #pragma unroll
  for (int i = 0; i < 8; ++i) {
    int s = (i << 8) + t;
    int d = s >> 2, k8 = (s & 3) << 3;
    *(bf16x8*)&ETl[d][k8] = *(const bf16x8*)(et + d * 32 + k8);
  }
  __syncthreads();
  bf16x8 a[4];
  #pragma unroll
  for (int rt = 0; rt < 4; ++rt)
    a[rt] = *(const bf16x8*)&Afl[(rt << 4) + lr][lq << 3];
  f32x4 z = {0.f, 0.f, 0.f, 0.f};
  #pragma unroll
  for (int ct = 0; ct < 8; ++ct) {
    bf16x8 bb = *(const bf16x8*)&ETl[(w << 7) + (ct << 4) + lr][lq << 3];
    #pragma unroll
    for (int rt = 0; rt < 4; ++rt) {
      f32x4 o = __builtin_amdgcn_mfma_f32_16x16x32_bf16(a[rt], bb, z, 0, 0, 0);
      #pragma unroll
      for (int j = 0; j < 4; ++j)
        Ol[(rt << 4) + (lq << 2) + j][(w << 7) + (ct << 4) + lr] = f2bf(o[j]);
    }
  }
  __syncthreads();
  // out = f32(gated + anchor), float4 stores
  #pragma unroll
  for (int it = 0; it < 32; ++it) {
    int s = (it << 8) + t;
    int r = s >> 7, c4 = (s & 127) << 2;
    s16x4 g4 = *(const s16x4*)(gated + (row0 + r) * 512 + c4);
    s16x4 a4 = *(const s16x4*)(&Ol[0][0] + r * 520 + c4);
    float4 o;
    o.x = bf2f((u16)g4[0]) + bf2f((u16)a4[0]);
    o.y = bf2f((u16)g4[1]) + bf2f((u16)a4[1]);
    o.z = bf2f((u16)g4[2]) + bf2f((u16)a4[2]);
    o.w = bf2f((u16)g4[3]) + bf2f((u16)a4[3]);
    *(float4*)(out + (row0 + r) * 512 + c4) = o;
  }
}

extern "C" void kernel_launch(void* const* d_in, const int* in_sizes, int n_in,
                              void* d_out, int out_size, void* d_ws, size_t ws_size,
                              hipStream_t stream) {
  (void)in_sizes; (void)n_in; (void)out_size;
  if (ws_size < WS_NEEDED) return;
  const float* feat = (const float*)d_in[0];
  const float* sfp  = (const float*)d_in[1];
  const float* tfp  = (const float*)d_in[2];
  const float* wf1  = (const float*)d_in[3];
  const float* bf1  = (const float*)d_in[4];
  const float* wf2  = (const float*)d_in[5];
  const float* wc   = (const float*)d_in[7];
  const float* bc   = (const float*)d_in[8];
  const float* wg1  = (const float*)d_in[9];
  const float* bg1  = (const float*)d_in[10];
  const float* wg2  = (const float*)d_in[11];
  const float* bg2  = (const float*)d_in[12];
  const float* E    = (const float*)d_in[13];
  const float* wfp  = (const float*)d_in[14];
  const float* bfp  = (const float*)d_in[15];
  const float* wfq  = (const float*)d_in[16];
  const float* bfq  = (const float*)d_in[17];

  char* ws = (char*)d_ws;
  float* grad   = (float*)(ws + OFF_GRAD);
  float* sumsq  = (float*)(ws + OFF_SUMSQ);
  float* consts = (float*)(ws + OFF_CONSTS);
  u16* ws16  = (u16*)ws;
  u16* wf1t  = (u16*)(ws + OFF_WF1T);
  u16* wg2t  = (u16*)(ws + OFF_WG2T);
  u16* wfpt  = (u16*)(ws + OFF_WFPT);
  u16* et    = (u16*)(ws + OFF_ET);
  u16* aff   = (u16*)(ws + OFF_AFF);
  u16* gated = (u16*)(ws + OFF_GATED);
  u16* yscr  = (u16*)d_out;                      // bf16 y scratch: first half of f32 d_out
  u16* featbf = (u16*)d_out + 33554432;          // bf16 feat: second half of d_out
                                                 // (dead before k_proj writes y / k_out writes out)
  float* out = (float*)d_out;

  hipMemsetAsync(ws + OFF_SUMSQ, 0, 262144, stream);
  k_cvt<<<dim3(16384), dim3(256), 0, stream>>>(feat, featbf);
  k_pre<<<dim3(10), dim3(256), 0, stream>>>(sfp, tfp, wf1, bf1, wc, bc, wg1, bg1, wfq, bfq, E, consts);
  k_transpose<<<dim3(912), dim3(256), 0, stream>>>(wf1, wg2, wfp, E, ws16);
  k_potential<<<dim3(4, 512), dim3(256), 0, stream>>>(featbf, wf1t, wf2, consts, grad);
  k_gate<<<dim3(4, 512), dim3(256), 0, stream>>>(featbf, grad, wg1, wg2t, bg2, consts, gated);
  k_proj<<<dim3(2, 512), dim3(256), 0, stream>>>(gated, wfpt, bfp, yscr, sumsq);
  k_aff<<<dim3(256), dim3(256), 0, stream>>>(yscr, E, sumsq, consts, aff);
  k_out<<<dim3(1024), dim3(256), 0, stream>>>(gated, aff, et, out);
}

// Round 3
// 635.833 us; speedup vs baseline: 1.0153x; 1.0153x over previous
//
#include <hip/hip_runtime.h>
#include <hip/hip_bf16.h>

typedef unsigned short u16;
typedef __attribute__((ext_vector_type(8))) __bf16 bf16x8;
typedef __attribute__((ext_vector_type(8))) short  s16x8;
typedef __attribute__((ext_vector_type(4))) short  s16x4;
typedef __attribute__((ext_vector_type(4))) float  f32x4;

#define NB 65536
// ws byte offsets
#define OFF_GRAD   0u
#define OFF_SUMSQ  1048576u
#define OFF_CONSTS 1310720u
#define OFF_WF1T   1327104u
#define OFF_WG2T   2375680u
#define OFF_WFPT   2637824u
#define OFF_ET     3162112u
#define OFF_AFF    3194880u
#define OFF_GATED  7389184u
#define WS_NEEDED  74498048u
// consts float indices
#define CI_SRC   0
#define CI_TGT   1024
#define CI_C0    2048
#define CI_INVE  2304
#define CI_ABIAS 2336

__device__ inline float bf2f(u16 u) { union { unsigned int i; float f; } v; v.i = ((unsigned int)u) << 16; return v.f; }
__device__ inline u16 f2bf(float f) { union { float f; unsigned int i; } v; v.f = f; return (u16)((v.i + 0x7fffu + ((v.i >> 16) & 1u)) >> 16); }
// tanh-approx gelu, max abs err ~3e-4 (threshold is 5.4e-2)
__device__ inline float gelu(float x) {
  float z = 1.5957691216f * x * (1.0f + 0.044715f * x * x);
  return x * __builtin_amdgcn_rcpf(1.0f + __expf(-z));
}
__device__ inline float sigm(float x) { return __builtin_amdgcn_rcpf(1.0f + __expf(-x)); }

// async global->LDS, 16B per lane. LDS dest = wave-uniform base + lane*16.
typedef __attribute__((address_space(3))) unsigned int as3_u32;
typedef __attribute__((address_space(1))) unsigned int as1_u32;
__device__ __forceinline__ void gload16(const u16* g, u16* l) {
  __builtin_amdgcn_global_load_lds((const as1_u32*)g, (as3_u32*)l, 16, 0, 0);
}

// ---------------- feat f32 -> bf16 (one-time, memory-bound) ----------------
__global__ __launch_bounds__(256) void k_cvt(const float* __restrict__ feat, u16* __restrict__ featbf) {
  int idx = (blockIdx.x << 8) + threadIdx.x;   // 8 elems/thread
  const float4* src = (const float4*)feat + (idx << 1);
  float4 v0 = src[0], v1 = src[1];
  s16x8 o;
  o[0] = (short)f2bf(v0.x); o[1] = (short)f2bf(v0.y);
  o[2] = (short)f2bf(v0.z); o[3] = (short)f2bf(v0.w);
  o[4] = (short)f2bf(v1.x); o[5] = (short)f2bf(v1.y);
  o[6] = (short)f2bf(v1.z); o[7] = (short)f2bf(v1.w);
  *(s16x8*)(featbf + (idx << 3)) = o;
}

// ---------------- precompute (batch-independent constants) ----------------
__global__ __launch_bounds__(256) void k_pre(
    const float* __restrict__ sfp, const float* __restrict__ tfp,
    const float* __restrict__ wf1, const float* __restrict__ bf1,
    const float* __restrict__ wc,  const float* __restrict__ bc,
    const float* __restrict__ wg1, const float* __restrict__ bg1,
    const float* __restrict__ wfq, const float* __restrict__ bfq,
    const float* __restrict__ E,   float* __restrict__ consts)
{
  __shared__ float s_s[64], s_t[64], s_c[4], s_fp[512];
  const int t = threadIdx.x;
  const int b = blockIdx.x;
  if (t < 64) { s_s[t] = sfp[t]; s_t[t] = tfp[t]; }
  __syncthreads();
  if (b < 8) {
    if (t < 128) {
      int n = b * 128 + t;
      int f = n >> 8, h = n & 255;
      float as = bf1[f * 256 + h];
      float at = as;
      const float* col = wf1 + f * 147456 + 512 * 256 + h;  // wf1[f][512+j][h]
      #pragma unroll 8
      for (int j = 0; j < 64; ++j) {
        float wv = col[j * 256];
        as += s_s[j] * wv; at += s_t[j] * wv;
      }
      consts[CI_SRC + n] = as;
      consts[CI_TGT + n] = at;
    }
  } else if (b == 8) {
    if (t < 4) {
      float a = bc[t];
      for (int j = 0; j < 64; ++j)
        a += s_s[j] * wc[j * 4 + t] + s_t[j] * wc[(64 + j) * 4 + t];
      s_c[t] = tanhf(a);
    }
    __syncthreads();
    float a = bg1[t];
    #pragma unroll
    for (int f = 0; f < 4; ++f) a += s_c[f] * wg1[(4 + f) * 256 + t];
    for (int j = 0; j < 64; ++j) a += s_s[j] * wg1[(8 + j) * 256 + t];
    consts[CI_C0 + t] = a;
  } else {
    for (int d = t; d < 512; d += 256) {
      float a = bfq[d];
      for (int j = 0; j < 64; ++j) a += s_s[j] * wfq[j * 512 + d];
      s_fp[d] = a;
    }
    __syncthreads();
    if (t < 32) {
      float ss = 0.f, dot = 0.f;
      for (int d = 0; d < 512; ++d) {
        float e = E[t * 512 + d];
        ss += e * e; dot += e * s_fp[d];
      }
      float inv = 1.0f / fmaxf(sqrtf(ss), 1e-12f);
      consts[CI_INVE + t] = inv;
      consts[CI_ABIAS + t] = 0.3f * inv * dot;
    }
  }
}

// ---------------- f32 weights -> bf16 transposed [N][K] for MFMA B-frags ----------------
__global__ __launch_bounds__(256) void k_transpose(
    const float* __restrict__ wf1, const float* __restrict__ wg2,
    const float* __restrict__ wfp, const float* __restrict__ E,
    u16* __restrict__ ws16)
{
  int tile = blockIdx.x;
  const float* src; u16* dst; int K, N, tl;
  if (tile < 512)      { int f = tile >> 7; tl = tile & 127; src = wf1 + f * 147456; dst = ws16 + (OFF_WF1T >> 1) + f * 131072; K = 512; N = 256; }
  else if (tile < 640) { tl = tile - 512; src = wg2; dst = ws16 + (OFF_WG2T >> 1); K = 256; N = 512; }
  else if (tile < 896) { tl = tile - 640; src = wfp; dst = ws16 + (OFF_WFPT >> 1); K = 512; N = 512; }
  else                 { tl = tile - 896; src = E;   dst = ws16 + (OFF_ET   >> 1); K = 32;  N = 512; }
  int ntn = N >> 5;
  int r0 = (tl / ntn) << 5, c0 = (tl % ntn) << 5;
  __shared__ float T[32][33];
  const int t = threadIdx.x;
  {
    int r = t >> 3, c4 = (t & 7) << 2;
    float4 v = *(const float4*)(src + (r0 + r) * N + c0 + c4);
    T[r][c4] = v.x; T[r][c4 + 1] = v.y; T[r][c4 + 2] = v.z; T[r][c4 + 3] = v.w;
  }
  __syncthreads();
  {
    int c = t >> 3, r4 = (t & 7) << 2;
    s16x4 v;
    v[0] = (short)f2bf(T[r4 + 0][c]); v[1] = (short)f2bf(T[r4 + 1][c]);
    v[2] = (short)f2bf(T[r4 + 2][c]); v[3] = (short)f2bf(T[r4 + 3][c]);
    *(s16x4*)(dst + (c0 + c) * K + r0 + r4) = v;
  }
}

// ---------------- potential GEMM + gelu-difference reduction -> gradient ----------------
// 2-phase double-buffered LDS (prefetch k+1 before compute k), XOR-swizzled tiles,
// XCD-aware block swizzle.
__global__ __launch_bounds__(256, 2) void k_potential(
    const u16* __restrict__ featbf, const u16* __restrict__ wf1t,
    const float* __restrict__ wf2,  const float* __restrict__ consts,
    float* __restrict__ grad)
{
  __shared__ u16 Al[2][128][32];
  __shared__ u16 Bl[2][256][32];
  const int wg = blockIdx.x;                  // 2048 wgs, %8==0 -> bijective
  const int s  = ((wg & 7) << 8) + (wg >> 3); // same-XCD chunks: 4 f-blocks x 64 rows
  const int f  = s & 3;
  const int col0 = f << 8;
  const int row0 = (s >> 2) << 7;
  const int t = threadIdx.x;
  const int w = t >> 6, lane = t & 63, lr = lane & 15, lq = lane >> 4;
  const int gr  = lane >> 2;
  const int gcs = ((lane & 3) ^ ((lane >> 3) & 3)) << 3;  // pre-swizzled global col
  const int ca  = (lq ^ ((lr >> 1) & 3)) << 3;            // swizzled LDS read col

  f32x4 acc[2][16];
  #pragma unroll
  for (int i = 0; i < 2; ++i)
    #pragma unroll
    for (int j = 0; j < 16; ++j) { f32x4 z = {0.f, 0.f, 0.f, 0.f}; acc[i][j] = z; }

#define STAGE_P(buf, k0) { \
    _Pragma("unroll") for (int j = 0; j < 2; ++j) { int rb = (j << 6) + (w << 4); \
      gload16(featbf + (row0 + rb + gr) * 512 + (k0) + gcs, &Al[buf][rb][0]); } \
    _Pragma("unroll") for (int j = 0; j < 4; ++j) { int rb = (j << 6) + (w << 4); \
      gload16(wf1t + (col0 + rb + gr) * 512 + (k0) + gcs, &Bl[buf][rb][0]); } }

#define COMP_P(buf) { bf16x8 a[2]; \
    _Pragma("unroll") for (int rt = 0; rt < 2; ++rt) \
      a[rt] = *(const bf16x8*)&Al[buf][(w << 5) + (rt << 4) + lr][ca]; \
    _Pragma("unroll") for (int ct = 0; ct < 16; ++ct) { \
      bf16x8 bb = *(const bf16x8*)&Bl[buf][(ct << 4) + lr][ca]; \
      acc[0][ct] = __builtin_amdgcn_mfma_f32_16x16x32_bf16(a[0], bb, acc[0][ct], 0, 0, 0); \
      acc[1][ct] = __builtin_amdgcn_mfma_f32_16x16x32_bf16(a[1], bb, acc[1][ct], 0, 0, 0); } }

  STAGE_P(0, 0);
  __syncthreads();
  #pragma unroll
  for (int k0 = 0; k0 < 512; k0 += 64) {
    STAGE_P(1, k0 + 32);
    COMP_P(0);
    __syncthreads();
    if (k0 + 64 < 512) STAGE_P(0, k0 + 64);
    COMP_P(1);
    __syncthreads();
  }
#undef STAGE_P
#undef COMP_P
  float part[2][4] = {{0, 0, 0, 0}, {0, 0, 0, 0}};
  #pragma unroll
  for (int ct = 0; ct < 16; ++ct) {
    int n = col0 + (ct << 4) + lr;
    float so = consts[CI_SRC + n];
    float to = consts[CI_TGT + n];
    float w2 = wf2[n];
    #pragma unroll
    for (int rt = 0; rt < 2; ++rt)
      #pragma unroll
      for (int j = 0; j < 4; ++j) {
        float c = acc[rt][ct][j];
        part[rt][j] += (gelu(c + to) - gelu(c + so)) * w2;
      }
  }
  #pragma unroll
  for (int m = 1; m <= 8; m <<= 1)
    #pragma unroll
    for (int rt = 0; rt < 2; ++rt)
      #pragma unroll
      for (int j = 0; j < 4; ++j)
        part[rt][j] += __shfl_xor(part[rt][j], m, 64);
  if (lr == 0) {
    #pragma unroll
    for (int rt = 0; rt < 2; ++rt)
      #pragma unroll
      for (int j = 0; j < 4; ++j) {
        int r = row0 + (w << 5) + (rt << 4) + (lq << 2) + j;
        grad[r * 4 + f] = part[rt][j];
      }
  }
}

// ---------------- gate MLP + gated = features * gate ----------------
__global__ __launch_bounds__(256, 2) void k_gate(
    const u16* __restrict__ featbf, const float* __restrict__ grad,
    const float* __restrict__ wg1,  const u16* __restrict__ wg2t,
    const float* __restrict__ bg2,  const float* __restrict__ consts,
    u16* __restrict__ gated)
{
  __shared__ u16 Hl[32768];        // [128][256] XOR-swizzled; later gate tile [128][136]
  __shared__ u16 Bl[2][128][32];
  const int wg = blockIdx.x;
  const int s  = ((wg & 7) << 8) + (wg >> 3);
  const int col0 = (s & 3) << 7;
  const int row0 = (s >> 2) << 7;
  const int t = threadIdx.x;
  const int w = t >> 6, lane = t & 63, lr = lane & 15, lq = lane >> 4;
  const int gr  = lane >> 2;
  const int gcs = ((lane & 3) ^ ((lane >> 3) & 3)) << 3;
  const int ca  = (lq ^ ((lr >> 1) & 3)) << 3;

#define STAGE_G(buf, k0) { \
    _Pragma("unroll") for (int j = 0; j < 2; ++j) { int rb = (j << 6) + (w << 4); \
      gload16(wg2t + (col0 + rb + gr) * 256 + (k0) + gcs, &Bl[buf][rb][0]); } }

  STAGE_G(0, 0);   // issue before phase-1 VALU work: latency hidden

  // phase 1: Hl[r][h] = gelu(c0[h] + grad[r]·Wg1[0:4,h]), h = t, swizzled store
  {
    float wv[4], c0v = consts[CI_C0 + t];
    const int tc = t >> 3, tw = t & 7;
    #pragma unroll
    for (int f = 0; f < 4; ++f) wv[f] = wg1[f * 256 + t];
    for (int i = 0; i < 128; ++i) {
      float4 g = *(const float4*)(grad + ((row0 + i) << 2));
      float p = c0v + g.x * wv[0] + g.y * wv[1] + g.z * wv[2] + g.w * wv[3];
      Hl[i * 256 + ((tc ^ ((i >> 1) & 7)) << 3) + tw] = f2bf(gelu(p));
    }
  }
  f32x4 acc[2][8];
  #pragma unroll
  for (int i = 0; i < 2; ++i)
    #pragma unroll
    for (int j = 0; j < 8; ++j) { f32x4 z = {0.f, 0.f, 0.f, 0.f}; acc[i][j] = z; }

#define COMP_G(buf, k0) { bf16x8 a[2]; \
    _Pragma("unroll") for (int rt = 0; rt < 2; ++rt) { \
      int r = (w << 5) + (rt << 4) + lr; \
      int cq = (((k0) >> 3) + lq) ^ (lr >> 1); \
      a[rt] = *(const bf16x8*)&Hl[r * 256 + (cq << 3)]; } \
    _Pragma("unroll") for (int ct = 0; ct < 8; ++ct) { \
      bf16x8 bb = *(const bf16x8*)&Bl[buf][(ct << 4) + lr][ca]; \
      acc[0][ct] = __builtin_amdgcn_mfma_f32_16x16x32_bf16(a[0], bb, acc[0][ct], 0, 0, 0); \
      acc[1][ct] = __builtin_amdgcn_mfma_f32_16x16x32_bf16(a[1], bb, acc[1][ct], 0, 0, 0); } }

  __syncthreads();
  #pragma unroll
  for (int k0 = 0; k0 < 256; k0 += 64) {
    STAGE_G(1, k0 + 32);
    COMP_G(0, k0);
    __syncthreads();
    if (k0 + 64 < 256) STAGE_G(0, k0 + 64);
    COMP_G(1, k0 + 32);
    __syncthreads();
  }
#undef STAGE_G
#undef COMP_G
  u16* Gl = Hl;                  // gate tile [128][136]
  #pragma unroll
  for (int ct = 0; ct < 8; ++ct) {
    int n = col0 + (ct << 4) + lr;
    float bv = bg2[n];
    #pragma unroll
    for (int rt = 0; rt < 2; ++rt)
      #pragma unroll
      for (int j = 0; j < 4; ++j) {
        int r = (w << 5) + (rt << 4) + (lq << 2) + j;
        Gl[r * 136 + (ct << 4) + lr] = f2bf(sigm(acc[rt][ct][j] + bv));
      }
  }
  __syncthreads();
  #pragma unroll
  for (int it = 0; it < 8; ++it) {
    int s2 = (it << 8) + t;
    int r = s2 >> 4, c8 = (s2 & 15) << 3;
    s16x8 f8 = *(const s16x8*)(featbf + (row0 + r) * 512 + col0 + c8);
    s16x8 g8 = *(const s16x8*)(Gl + r * 136 + c8);
    s16x8 o;
    #pragma unroll
    for (int j = 0; j < 8; ++j)
      o[j] = (short)f2bf(bf2f((u16)f8[j]) * bf2f((u16)g8[j]));
    *(s16x8*)(gated + (row0 + r) * 512 + col0 + c8) = o;
  }
}

// ---------------- y = gated @ Wfp + bfp; row sum-of-squares; y -> d_out (scratch) ----------------
__global__ __launch_bounds__(256, 2) void k_proj(
    const u16* __restrict__ gated, const u16* __restrict__ wfpt,
    const float* __restrict__ bfp, u16* __restrict__ y,
    float* __restrict__ sumsq)
{
  __shared__ u16 U[33792];       // dbuf staging (2x12KB) then bounce [128][264]
  u16* A0 = U;                   // [128][32]
  u16* B0 = U + 4096;            // [256][32]
  u16* A1 = U + 12288;
  u16* B1 = U + 16384;
  const int wg = blockIdx.x;                  // 1024 wgs
  const int s  = ((wg & 7) << 7) + (wg >> 3);
  const int col0 = (s & 1) << 8;
  const int row0 = (s >> 1) << 7;
  const int t = threadIdx.x;
  const int w = t >> 6, lane = t & 63, lr = lane & 15, lq = lane >> 4;
  const int gr  = lane >> 2;
  const int gcs = ((lane & 3) ^ ((lane >> 3) & 3)) << 3;
  const int ca  = (lq ^ ((lr >> 1) & 3)) << 3;

  f32x4 acc[2][16];
  #pragma unroll
  for (int i = 0; i < 2; ++i)
    #pragma unroll
    for (int j = 0; j < 16; ++j) { f32x4 z = {0.f, 0.f, 0.f, 0.f}; acc[i][j] = z; }

#define STAGE_J(Ab, Bb, k0) { \
    _Pragma("unroll") for (int j = 0; j < 2; ++j) { int rb = (j << 6) + (w << 4); \
      gload16(gated + (row0 + rb + gr) * 512 + (k0) + gcs, Ab + rb * 32); } \
    _Pragma("unroll") for (int j = 0; j < 4; ++j) { int rb = (j << 6) + (w << 4); \
      gload16(wfpt + (col0 + rb + gr) * 512 + (k0) + gcs, Bb + rb * 32); } }

#define COMP_J(Ab, Bb) { bf16x8 a[2]; \
    _Pragma("unroll") for (int rt = 0; rt < 2; ++rt) \
      a[rt] = *(const bf16x8*)&Ab[((w << 5) + (rt << 4) + lr) * 32 + ca]; \
    _Pragma("unroll") for (int ct = 0; ct < 16; ++ct) { \
      bf16x8 bb = *(const bf16x8*)&Bb[((ct << 4) + lr) * 32 + ca]; \
      acc[0][ct] = __builtin_amdgcn_mfma_f32_16x16x32_bf16(a[0], bb, acc[0][ct], 0, 0, 0); \
      acc[1][ct] = __builtin_amdgcn_mfma_f32_16x16x32_bf16(a[1], bb, acc[1][ct], 0, 0, 0); } }

  STAGE_J(A0, B0, 0);
  __syncthreads();
  #pragma unroll
  for (int k0 = 0; k0 < 512; k0 += 64) {
    STAGE_J(A1, B1, k0 + 32);
    COMP_J(A0, B0);
    __syncthreads();
    if (k0 + 64 < 512) STAGE_J(A0, B0, k0 + 64);
    COMP_J(A1, B1);
    __syncthreads();
  }
#undef STAGE_J
#undef COMP_J
  float part[2][4] = {{0, 0, 0, 0}, {0, 0, 0, 0}};
  #pragma unroll
  for (int ct = 0; ct < 16; ++ct) {
    float bv = bfp[col0 + (ct << 4) + lr];
    #pragma unroll
    for (int rt = 0; rt < 2; ++rt)
      #pragma unroll
      for (int j = 0; j < 4; ++j) {
        acc[rt][ct][j] += bv;
        part[rt][j] += acc[rt][ct][j] * acc[rt][ct][j];
      }
  }
  #pragma unroll
  for (int m = 1; m <= 8; m <<= 1)
    #pragma unroll
    for (int rt = 0; rt < 2; ++rt)
      #pragma unroll
      for (int j = 0; j < 4; ++j)
        part[rt][j] += __shfl_xor(part[rt][j], m, 64);
  if (lr == 0) {
    #pragma unroll
    for (int rt = 0; rt < 2; ++rt)
      #pragma unroll
      for (int j = 0; j < 4; ++j)
        atomicAdd(&sumsq[row0 + (w << 5) + (rt << 4) + (lq << 2) + j], part[rt][j]);
  }
  u16* Yl = U;                          // bounce [128][264] (all staging reads drained)
  #pragma unroll
  for (int ct = 0; ct < 16; ++ct)
    #pragma unroll
    for (int rt = 0; rt < 2; ++rt)
      #pragma unroll
      for (int j = 0; j < 4; ++j) {
        int r = (w << 5) + (rt << 4) + (lq << 2) + j;
        Yl[r * 264 + (ct << 4) + lr] = f2bf(acc[rt][ct][j]);
      }
  __syncthreads();
  #pragma unroll
  for (int it = 0; it < 16; ++it) {
    int s2 = (it << 8) + t;
    int r = s2 >> 5, c8 = (s2 & 31) << 3;
    *(s16x8*)(y + (row0 + r) * 512 + col0 + c8) = *(const s16x8*)(Yl + r * 264 + c8);
  }
}

// ---------------- aff = softmax(normalize(y) @ anchors_norm^T + abias) ----------------
__global__ __launch_bounds__(256, 2) void k_aff(
    const u16* __restrict__ y, const float* __restrict__ E,
    const float* __restrict__ sumsq, const float* __restrict__ consts,
    u16* __restrict__ aff)
{
  __shared__ u16 El[32][520];
  __shared__ u16 Aa[2][256][32];
  const int row0 = blockIdx.x << 8;
  const int t = threadIdx.x;
  const int w = t >> 6, lane = t & 63, lr = lane & 15, lq = lane >> 4;
  const int gr  = lane >> 2;
  const int gcs = ((lane & 3) ^ ((lane >> 3) & 3)) << 3;
  const int ca  = (lq ^ ((lr >> 1) & 3)) << 3;

#define STAGE_A(buf, k0) { \
    _Pragma("unroll") for (int j = 0; j < 4; ++j) { int rb = (j << 6) + (w << 4); \
      gload16(y + (row0 + rb + gr) * 512 + (k0) + gcs, &Aa[buf][rb][0]); } }

  STAGE_A(0, 0);
  #pragma unroll
  for (int i = 0; i < 16; ++i) {
    int s = (i << 8) + t;
    int a = s >> 7, c4 = (s & 127) << 2;
    float4 v = *(const float4*)(E + a * 512 + c4);
    s16x4 b;
    b[0] = (short)f2bf(v.x); b[1] = (short)f2bf(v.y);
    b[2] = (short)f2bf(v.z); b[3] = (short)f2bf(v.w);
    *(s16x4*)&El[a][c4] = b;
  }
  f32x4 acc[4][2];
  #pragma unroll
  for (int i = 0; i < 4; ++i)
    #pragma unroll
    for (int j = 0; j < 2; ++j) { f32x4 z = {0.f, 0.f, 0.f, 0.f}; acc[i][j] = z; }

#define COMP_A(buf, k0) { \
    bf16x8 b0 = *(const bf16x8*)&El[lr][(k0) + (lq << 3)]; \
    bf16x8 b1 = *(const bf16x8*)&El[16 + lr][(k0) + (lq << 3)]; \
    _Pragma("unroll") for (int rt = 0; rt < 4; ++rt) { \
      bf16x8 a = *(const bf16x8*)&Aa[buf][(w << 6) + (rt << 4) + lr][ca]; \
      acc[rt][0] = __builtin_amdgcn_mfma_f32_16x16x32_bf16(a, b0, acc[rt][0], 0, 0, 0); \
      acc[rt][1] = __builtin_amdgcn_mfma_f32_16x16x32_bf16(a, b1, acc[rt][1], 0, 0, 0); } }

  __syncthreads();
  #pragma unroll
  for (int k0 = 0; k0 < 512; k0 += 64) {
    STAGE_A(1, k0 + 32);
    COMP_A(0, k0);
    __syncthreads();
    if (k0 + 64 < 512) STAGE_A(0, k0 + 64);
    COMP_A(1, k0 + 32);
    __syncthreads();
  }
#undef STAGE_A
#undef COMP_A
  float iv0 = consts[CI_INVE + lr],  iv1 = consts[CI_INVE + 16 + lr];
  float ab0 = consts[CI_ABIAS + lr], ab1 = consts[CI_ABIAS + 16 + lr];
  #pragma unroll
  for (int rt = 0; rt < 4; ++rt) {
    #pragma unroll
    for (int j = 0; j < 4; ++j) {
      int r = row0 + (w << 6) + (rt << 4) + (lq << 2) + j;
      float invn = 1.0f / fmaxf(sqrtf(sumsq[r]), 1e-12f);
      float v0 = acc[rt][0][j] * iv0 * invn + ab0;
      float v1 = acc[rt][1][j] * iv1 * invn + ab1;
      float mx = fmaxf(v0, v1);
      #pragma unroll
      for (int m = 1; m <= 8; m <<= 1) mx = fmaxf(mx, __shfl_xor(mx, m, 64));
      float e0 = __expf(v0 - mx), e1 = __expf(v1 - mx);
      float sm = e0 + e1;
      #pragma unroll
      for (int m = 1; m <= 8; m <<= 1) sm += __shfl_xor(sm, m, 64);
      float rs = 1.0f / sm;
      aff[r * 32 + lr]      = f2bf(e0 * rs);
      aff[r * 32 + 16 + lr] = f2bf(e1 * rs);
    }
  }
}

// ---------------- out = gated + aff @ E  (f32 output!) ----------------
__global__ __launch_bounds__(256, 2) void k_out(
    const u16* __restrict__ gated, const u16* __restrict__ aff,
    const u16* __restrict__ et, float* __restrict__ out)
{
  __shared__ u16 ETl[512][40];
  __shared__ u16 Afl[64][40];
  __shared__ u16 Ol[64][520];
  const int row0 = blockIdx.x << 6;
  const int t = threadIdx.x;
  const int w = t >> 6, lane = t & 63, lr = lane & 15, lq = lane >> 4;
  {
    int r = t >> 2, k8 = (t & 3) << 3;
    *(bf16x8*)&Afl[r][k8] = *(const bf16x8*)(aff + (row0 + r) * 32 + k8);
  }
  #pragma unroll
  for (int i = 0; i < 8; ++i) {
    int s = (i << 8) + t;
    int d = s >> 2, k8 = (s & 3) << 3;
    *(bf16x8*)&ETl[d][k8] = *(const bf16x8*)(et + d * 32 + k8);
  }
  __syncthreads();
  bf16x8 a[4];
  #pragma unroll
  for (int rt = 0; rt < 4; ++rt)
    a[rt] = *(const bf16x8*)&Afl[(rt << 4) + lr][lq << 3];
  f32x4 z = {0.f, 0.f, 0.f, 0.f};
  #pragma unroll
  for (int ct = 0; ct < 8; ++ct) {
    bf16x8 bb = *(const bf16x8*)&ETl[(w << 7) + (ct << 4) + lr][lq << 3];
    #pragma unroll
    for (int rt = 0; rt < 4; ++rt) {
      f32x4 o = __builtin_amdgcn_mfma_f32_16x16x32_bf16(a[rt], bb, z, 0, 0, 0);
      #pragma unroll
      for (int j = 0; j < 4; ++j)
        Ol[(rt << 4) + (lq << 2) + j][(w << 7) + (ct << 4) + lr] = f2bf(o[j]);
    }
  }
  __syncthreads();
  // out = f32(gated + anchor), float4 stores
  #pragma unroll
  for (int it = 0; it < 32; ++it) {
    int s = (it << 8) + t;
    int r = s >> 7, c4 = (s & 127) << 2;
    s16x4 g4 = *(const s16x4*)(gated + (row0 + r) * 512 + c4);
    s16x4 a4 = *(const s16x4*)(&Ol[0][0] + r * 520 + c4);
    float4 o;
    o.x = bf2f((u16)g4[0]) + bf2f((u16)a4[0]);
    o.y = bf2f((u16)g4[1]) + bf2f((u16)a4[1]);
    o.z = bf2f((u16)g4[2]) + bf2f((u16)a4[2]);
    o.w = bf2f((u16)g4[3]) + bf2f((u16)a4[3]);
    *(float4*)(out + (row0 + r) * 512 + c4) = o;
  }
}

extern "C" void kernel_launch(void* const* d_in, const int* in_sizes, int n_in,
                              void* d_out, int out_size, void* d_ws, size_t ws_size,
                              hipStream_t stream) {
  (void)in_sizes; (void)n_in; (void)out_size;
  if (ws_size < WS_NEEDED) return;
  const float* feat = (const float*)d_in[0];
  const float* sfp  = (const float*)d_in[1];
  const float* tfp  = (const float*)d_in[2];
  const float* wf1  = (const float*)d_in[3];
  const float* bf1  = (const float*)d_in[4];
  const float* wf2  = (const float*)d_in[5];
  const float* wc   = (const float*)d_in[7];
  const float* bc   = (const float*)d_in[8];
  const float* wg1  = (const float*)d_in[9];
  const float* bg1  = (const float*)d_in[10];
  const float* wg2  = (const float*)d_in[11];
  const float* bg2  = (const float*)d_in[12];
  const float* E    = (const float*)d_in[13];
  const float* wfp  = (const float*)d_in[14];
  const float* bfp  = (const float*)d_in[15];
  const float* wfq  = (const float*)d_in[16];
  const float* bfq  = (const float*)d_in[17];

  char* ws = (char*)d_ws;
  float* grad   = (float*)(ws + OFF_GRAD);
  float* sumsq  = (float*)(ws + OFF_SUMSQ);
  float* consts = (float*)(ws + OFF_CONSTS);
  u16* ws16  = (u16*)ws;
  u16* wf1t  = (u16*)(ws + OFF_WF1T);
  u16* wg2t  = (u16*)(ws + OFF_WG2T);
  u16* wfpt  = (u16*)(ws + OFF_WFPT);
  u16* et    = (u16*)(ws + OFF_ET);
  u16* aff   = (u16*)(ws + OFF_AFF);
  u16* gated = (u16*)(ws + OFF_GATED);
  u16* yscr  = (u16*)d_out;                      // bf16 y scratch: first half of f32 d_out
  u16* featbf = (u16*)d_out + 33554432;          // bf16 feat: second half of d_out
  float* out = (float*)d_out;

  hipMemsetAsync(ws + OFF_SUMSQ, 0, 262144, stream);
  k_cvt<<<dim3(16384), dim3(256), 0, stream>>>(feat, featbf);
  k_pre<<<dim3(10), dim3(256), 0, stream>>>(sfp, tfp, wf1, bf1, wc, bc, wg1, bg1, wfq, bfq, E, consts);
  k_transpose<<<dim3(912), dim3(256), 0, stream>>>(wf1, wg2, wfp, E, ws16);
  k_potential<<<dim3(2048), dim3(256), 0, stream>>>(featbf, wf1t, wf2, consts, grad);
  k_gate<<<dim3(2048), dim3(256), 0, stream>>>(featbf, grad, wg1, wg2t, bg2, consts, gated);
  k_proj<<<dim3(1024), dim3(256), 0, stream>>>(gated, wfpt, bfp, yscr, sumsq);
  k_aff<<<dim3(256), dim3(256), 0, stream>>>(yscr, E, sumsq, consts, aff);
  k_out<<<dim3(1024), dim3(256), 0, stream>>>(gated, aff, et, out);
}

// Round 4
// 608.199 us; speedup vs baseline: 1.0615x; 1.0454x over previous
//
#include <hip/hip_runtime.h>
#include <hip/hip_bf16.h>

typedef unsigned short u16;
typedef __attribute__((ext_vector_type(8))) __bf16 bf16x8;
typedef __attribute__((ext_vector_type(8))) short  s16x8;
typedef __attribute__((ext_vector_type(4))) short  s16x4;
typedef __attribute__((ext_vector_type(4))) float  f32x4;

#define NB 65536
// ws byte offsets
#define OFF_GRAD   0u
#define OFF_SUMSQ  1048576u
#define OFF_CONSTS 1310720u
#define OFF_WF1T   1327104u
#define OFF_WG2T   2375680u
#define OFF_WFPT   2637824u
#define OFF_ET     3162112u
#define OFF_AFF    3194880u
#define OFF_GATED  7389184u
#define WS_NEEDED  74498048u
// consts float indices
#define CI_SRC   0
#define CI_TGT   1024
#define CI_C0    2048
#define CI_INVE  2304
#define CI_ABIAS 2336

__device__ inline float bf2f(u16 u) { union { unsigned int i; float f; } v; v.i = ((unsigned int)u) << 16; return v.f; }
__device__ inline u16 f2bf(float f) { union { float f; unsigned int i; } v; v.f = f; return (u16)((v.i + 0x7fffu + ((v.i >> 16) & 1u)) >> 16); }
// tanh-approx gelu, max abs err ~3e-4 (threshold is 5.4e-2)
__device__ inline float gelu(float x) {
  float z = 1.5957691216f * x * (1.0f + 0.044715f * x * x);
  return x * __builtin_amdgcn_rcpf(1.0f + __expf(-z));
}
__device__ inline float sigm(float x) { return __builtin_amdgcn_rcpf(1.0f + __expf(-x)); }

// async global->LDS, 16B per lane. LDS dest = wave-uniform base + lane*16.
typedef __attribute__((address_space(3))) unsigned int as3_u32;
typedef __attribute__((address_space(1))) unsigned int as1_u32;
__device__ __forceinline__ void gload16(const u16* g, u16* l) {
  __builtin_amdgcn_global_load_lds((const as1_u32*)g, (as3_u32*)l, 16, 0, 0);
}

// ---------------- feat f32 -> bf16 (one-time, memory-bound) ----------------
__global__ __launch_bounds__(256) void k_cvt(const float* __restrict__ feat, u16* __restrict__ featbf) {
  int idx = (blockIdx.x << 8) + threadIdx.x;   // 8 elems/thread
  const float4* src = (const float4*)feat + (idx << 1);
  float4 v0 = src[0], v1 = src[1];
  s16x8 o;
  o[0] = (short)f2bf(v0.x); o[1] = (short)f2bf(v0.y);
  o[2] = (short)f2bf(v0.z); o[3] = (short)f2bf(v0.w);
  o[4] = (short)f2bf(v1.x); o[5] = (short)f2bf(v1.y);
  o[6] = (short)f2bf(v1.z); o[7] = (short)f2bf(v1.w);
  *(s16x8*)(featbf + (idx << 3)) = o;
}

// ---------------- precompute (batch-independent constants) ----------------
__global__ __launch_bounds__(256) void k_pre(
    const float* __restrict__ sfp, const float* __restrict__ tfp,
    const float* __restrict__ wf1, const float* __restrict__ bf1,
    const float* __restrict__ wc,  const float* __restrict__ bc,
    const float* __restrict__ wg1, const float* __restrict__ bg1,
    const float* __restrict__ wfq, const float* __restrict__ bfq,
    const float* __restrict__ E,   float* __restrict__ consts)
{
  __shared__ float s_s[64], s_t[64], s_c[4], s_fp[512];
  const int t = threadIdx.x;
  const int b = blockIdx.x;
  if (t < 64) { s_s[t] = sfp[t]; s_t[t] = tfp[t]; }
  __syncthreads();
  if (b < 8) {
    if (t < 128) {
      int n = b * 128 + t;
      int f = n >> 8, h = n & 255;
      float as = bf1[f * 256 + h];
      float at = as;
      const float* col = wf1 + f * 147456 + 512 * 256 + h;  // wf1[f][512+j][h]
      #pragma unroll 8
      for (int j = 0; j < 64; ++j) {
        float wv = col[j * 256];
        as += s_s[j] * wv; at += s_t[j] * wv;
      }
      consts[CI_SRC + n] = as;
      consts[CI_TGT + n] = at;
    }
  } else if (b == 8) {
    if (t < 4) {
      float a = bc[t];
      for (int j = 0; j < 64; ++j)
        a += s_s[j] * wc[j * 4 + t] + s_t[j] * wc[(64 + j) * 4 + t];
      s_c[t] = tanhf(a);
    }
    __syncthreads();
    float a = bg1[t];
    #pragma unroll
    for (int f = 0; f < 4; ++f) a += s_c[f] * wg1[(4 + f) * 256 + t];
    for (int j = 0; j < 64; ++j) a += s_s[j] * wg1[(8 + j) * 256 + t];
    consts[CI_C0 + t] = a;
  } else {
    for (int d = t; d < 512; d += 256) {
      float a = bfq[d];
      for (int j = 0; j < 64; ++j) a += s_s[j] * wfq[j * 512 + d];
      s_fp[d] = a;
    }
    __syncthreads();
    if (t < 32) {
      float ss = 0.f, dot = 0.f;
      for (int d = 0; d < 512; ++d) {
        float e = E[t * 512 + d];
        ss += e * e; dot += e * s_fp[d];
      }
      float inv = 1.0f / fmaxf(sqrtf(ss), 1e-12f);
      consts[CI_INVE + t] = inv;
      consts[CI_ABIAS + t] = 0.3f * inv * dot;
    }
  }
}

// ---------------- f32 weights -> bf16 transposed [N][K] for MFMA B-frags ----------------
__global__ __launch_bounds__(256) void k_transpose(
    const float* __restrict__ wf1, const float* __restrict__ wg2,
    const float* __restrict__ wfp, const float* __restrict__ E,
    u16* __restrict__ ws16)
{
  int tile = blockIdx.x;
  const float* src; u16* dst; int K, N, tl;
  if (tile < 512)      { int f = tile >> 7; tl = tile & 127; src = wf1 + f * 147456; dst = ws16 + (OFF_WF1T >> 1) + f * 131072; K = 512; N = 256; }
  else if (tile < 640) { tl = tile - 512; src = wg2; dst = ws16 + (OFF_WG2T >> 1); K = 256; N = 512; }
  else if (tile < 896) { tl = tile - 640; src = wfp; dst = ws16 + (OFF_WFPT >> 1); K = 512; N = 512; }
  else                 { tl = tile - 896; src = E;   dst = ws16 + (OFF_ET   >> 1); K = 32;  N = 512; }
  int ntn = N >> 5;
  int r0 = (tl / ntn) << 5, c0 = (tl % ntn) << 5;
  __shared__ float T[32][33];
  const int t = threadIdx.x;
  {
    int r = t >> 3, c4 = (t & 7) << 2;
    float4 v = *(const float4*)(src + (r0 + r) * N + c0 + c4);
    T[r][c4] = v.x; T[r][c4 + 1] = v.y; T[r][c4 + 2] = v.z; T[r][c4 + 3] = v.w;
  }
  __syncthreads();
  {
    int c = t >> 3, r4 = (t & 7) << 2;
    s16x4 v;
    v[0] = (short)f2bf(T[r4 + 0][c]); v[1] = (short)f2bf(T[r4 + 1][c]);
    v[2] = (short)f2bf(T[r4 + 2][c]); v[3] = (short)f2bf(T[r4 + 3][c]);
    *(s16x4*)(dst + (c0 + c) * K + r0 + r4) = v;
  }
}

// ---------------- potential GEMM + gelu-difference reduction -> gradient ----------------
// 3-buffer pipeline, counted vmcnt(6) + raw s_barrier: staging loads stay in flight
// across barriers (T4). XOR-swizzled tiles, XCD-aware block swizzle.
__global__ __launch_bounds__(256, 2) void k_potential(
    const u16* __restrict__ featbf, const u16* __restrict__ wf1t,
    const float* __restrict__ wf2,  const float* __restrict__ consts,
    float* __restrict__ grad)
{
  __shared__ u16 U[36864];   // 3 x (A 4096 + B 8192) u16 = 72 KB
  const int wg = blockIdx.x;                  // 2048 wgs, %8==0 -> bijective
  const int s  = ((wg & 7) << 8) + (wg >> 3); // same-XCD chunks
  const int f  = s & 3;
  const int col0 = f << 8;
  const int row0 = (s >> 2) << 7;
  const int t = threadIdx.x;
  const int w = t >> 6, lane = t & 63, lr = lane & 15, lq = lane >> 4;
  const int gr  = lane >> 2;
  const int gcs = ((lane & 3) ^ ((lane >> 3) & 3)) << 3;  // pre-swizzled global col
  const int ca  = (lq ^ ((lr >> 1) & 3)) << 3;            // swizzled LDS read col

  f32x4 acc[2][16];
  #pragma unroll
  for (int i = 0; i < 2; ++i)
    #pragma unroll
    for (int j = 0; j < 16; ++j) { f32x4 z = {0.f, 0.f, 0.f, 0.f}; acc[i][j] = z; }

#define STAGE_P(bi, k0) { u16* bas = U + (bi) * 12288; \
    _Pragma("unroll") for (int j = 0; j < 2; ++j) { int rb = (j << 6) + (w << 4); \
      gload16(featbf + (row0 + rb + gr) * 512 + (k0) + gcs, bas + rb * 32); } \
    _Pragma("unroll") for (int j = 0; j < 4; ++j) { int rb = (j << 6) + (w << 4); \
      gload16(wf1t + (col0 + rb + gr) * 512 + (k0) + gcs, bas + 4096 + rb * 32); } }

#define COMP_P(bi) { const u16* bas = U + (bi) * 12288; bf16x8 a[2]; \
    _Pragma("unroll") for (int rt = 0; rt < 2; ++rt) \
      a[rt] = *(const bf16x8*)&bas[((w << 5) + (rt << 4) + lr) * 32 + ca]; \
    _Pragma("unroll") for (int ct = 0; ct < 16; ++ct) { \
      bf16x8 bb = *(const bf16x8*)&bas[4096 + ((ct << 4) + lr) * 32 + ca]; \
      acc[0][ct] = __builtin_amdgcn_mfma_f32_16x16x32_bf16(a[0], bb, acc[0][ct], 0, 0, 0); \
      acc[1][ct] = __builtin_amdgcn_mfma_f32_16x16x32_bf16(a[1], bb, acc[1][ct], 0, 0, 0); } }

  STAGE_P(0, 0);
  STAGE_P(1, 32);
  #pragma unroll
  for (int tt = 0; tt < 16; ++tt) {
    if (tt < 15) asm volatile("s_waitcnt vmcnt(6)\n\ts_barrier" ::: "memory");
    else         asm volatile("s_waitcnt vmcnt(0)\n\ts_barrier" ::: "memory");
    if (tt < 14) STAGE_P((tt + 2) % 3, (tt + 2) * 32);
    COMP_P(tt % 3);
  }
#undef STAGE_P
#undef COMP_P
  float part[2][4] = {{0, 0, 0, 0}, {0, 0, 0, 0}};
  #pragma unroll
  for (int ct = 0; ct < 16; ++ct) {
    int n = col0 + (ct << 4) + lr;
    float so = consts[CI_SRC + n];
    float to = consts[CI_TGT + n];
    float w2 = wf2[n];
    #pragma unroll
    for (int rt = 0; rt < 2; ++rt)
      #pragma unroll
      for (int j = 0; j < 4; ++j) {
        float c = acc[rt][ct][j];
        part[rt][j] += (gelu(c + to) - gelu(c + so)) * w2;
      }
  }
  #pragma unroll
  for (int m = 1; m <= 8; m <<= 1)
    #pragma unroll
    for (int rt = 0; rt < 2; ++rt)
      #pragma unroll
      for (int j = 0; j < 4; ++j)
        part[rt][j] += __shfl_xor(part[rt][j], m, 64);
  if (lr == 0) {
    #pragma unroll
    for (int rt = 0; rt < 2; ++rt)
      #pragma unroll
      for (int j = 0; j < 4; ++j) {
        int r = row0 + (w << 5) + (rt << 4) + (lq << 2) + j;
        grad[r * 4 + f] = part[rt][j];
      }
  }
}

// ---------------- gate MLP + gated = features * gate ----------------
__global__ __launch_bounds__(256, 2) void k_gate(
    const u16* __restrict__ featbf, const float* __restrict__ grad,
    const float* __restrict__ wg1,  const u16* __restrict__ wg2t,
    const float* __restrict__ bg2,  const float* __restrict__ consts,
    u16* __restrict__ gated)
{
  __shared__ u16 Hl[32768];        // [128][256] XOR-swizzled; later gate tile [128][136]
  __shared__ u16 Bl[2][128][32];
  const int wg = blockIdx.x;
  const int s  = ((wg & 7) << 8) + (wg >> 3);
  const int col0 = (s & 3) << 7;
  const int row0 = (s >> 2) << 7;
  const int t = threadIdx.x;
  const int w = t >> 6, lane = t & 63, lr = lane & 15, lq = lane >> 4;
  const int gr  = lane >> 2;
  const int gcs = ((lane & 3) ^ ((lane >> 3) & 3)) << 3;
  const int ca  = (lq ^ ((lr >> 1) & 3)) << 3;

#define STAGE_G(buf, k0) { \
    _Pragma("unroll") for (int j = 0; j < 2; ++j) { int rb = (j << 6) + (w << 4); \
      gload16(wg2t + (col0 + rb + gr) * 256 + (k0) + gcs, &Bl[buf][rb][0]); } }

  STAGE_G(0, 0);   // issue before phase-1 VALU work: latency hidden

  // phase 1: Hl[r][h] = gelu(c0[h] + grad[r]·Wg1[0:4,h]), h = t, swizzled store
  {
    float wv[4], c0v = consts[CI_C0 + t];
    const int tc = t >> 3, tw = t & 7;
    #pragma unroll
    for (int f = 0; f < 4; ++f) wv[f] = wg1[f * 256 + t];
    for (int i = 0; i < 128; ++i) {
      float4 g = *(const float4*)(grad + ((row0 + i) << 2));
      float p = c0v + g.x * wv[0] + g.y * wv[1] + g.z * wv[2] + g.w * wv[3];
      Hl[i * 256 + ((tc ^ ((i >> 1) & 7)) << 3) + tw] = f2bf(gelu(p));
    }
  }
  f32x4 acc[2][8];
  #pragma unroll
  for (int i = 0; i < 2; ++i)
    #pragma unroll
    for (int j = 0; j < 8; ++j) { f32x4 z = {0.f, 0.f, 0.f, 0.f}; acc[i][j] = z; }

#define COMP_G(buf, k0) { bf16x8 a[2]; \
    _Pragma("unroll") for (int rt = 0; rt < 2; ++rt) { \
      int r = (w << 5) + (rt << 4) + lr; \
      int cq = (((k0) >> 3) + lq) ^ (lr >> 1); \
      a[rt] = *(const bf16x8*)&Hl[r * 256 + (cq << 3)]; } \
    _Pragma("unroll") for (int ct = 0; ct < 8; ++ct) { \
      bf16x8 bb = *(const bf16x8*)&Bl[buf][(ct << 4) + lr][ca]; \
      acc[0][ct] = __builtin_amdgcn_mfma_f32_16x16x32_bf16(a[0], bb, acc[0][ct], 0, 0, 0); \
      acc[1][ct] = __builtin_amdgcn_mfma_f32_16x16x32_bf16(a[1], bb, acc[1][ct], 0, 0, 0); } }

  __syncthreads();
  #pragma unroll
  for (int k0 = 0; k0 < 256; k0 += 64) {
    STAGE_G(1, k0 + 32);
    COMP_G(0, k0);
    __syncthreads();
    if (k0 + 64 < 256) STAGE_G(0, k0 + 64);
    COMP_G(1, k0 + 32);
    __syncthreads();
  }
#undef STAGE_G
#undef COMP_G
  u16* Gl = Hl;                  // gate tile [128][136]
  #pragma unroll
  for (int ct = 0; ct < 8; ++ct) {
    int n = col0 + (ct << 4) + lr;
    float bv = bg2[n];
    #pragma unroll
    for (int rt = 0; rt < 2; ++rt)
      #pragma unroll
      for (int j = 0; j < 4; ++j) {
        int r = (w << 5) + (rt << 4) + (lq << 2) + j;
        Gl[r * 136 + (ct << 4) + lr] = f2bf(sigm(acc[rt][ct][j] + bv));
      }
  }
  __syncthreads();
  #pragma unroll
  for (int it = 0; it < 8; ++it) {
    int s2 = (it << 8) + t;
    int r = s2 >> 4, c8 = (s2 & 15) << 3;
    s16x8 f8 = *(const s16x8*)(featbf + (row0 + r) * 512 + col0 + c8);
    s16x8 g8 = *(const s16x8*)(Gl + r * 136 + c8);
    s16x8 o;
    #pragma unroll
    for (int j = 0; j < 8; ++j)
      o[j] = (short)f2bf(bf2f((u16)f8[j]) * bf2f((u16)g8[j]));
    *(s16x8*)(gated + (row0 + r) * 512 + col0 + c8) = o;
  }
}

// ---------------- y = gated @ Wfp + bfp (LDS only); sumsq; S = y @ E_cols^T -> aff32 atomics ----------------
__global__ __launch_bounds__(256, 2) void k_proj(
    const u16* __restrict__ gated, const u16* __restrict__ wfpt,
    const float* __restrict__ bfp, const float* __restrict__ E,
    float* __restrict__ aff32, float* __restrict__ sumsq)
{
  __shared__ u16 U[36864];   // 3 x 12288 staging; epilogue: Yl[128][136] + El2[32][264]
  const int wg = blockIdx.x;                  // 1024 wgs
  const int s  = ((wg & 7) << 7) + (wg >> 3);
  const int col0 = (s & 1) << 8;
  const int row0 = (s >> 1) << 7;
  const int t = threadIdx.x;
  const int w = t >> 6, lane = t & 63, lr = lane & 15, lq = lane >> 4;
  const int gr  = lane >> 2;
  const int gcs = ((lane & 3) ^ ((lane >> 3) & 3)) << 3;
  const int ca  = (lq ^ ((lr >> 1) & 3)) << 3;

  f32x4 acc[2][16];
  #pragma unroll
  for (int i = 0; i < 2; ++i)
    #pragma unroll
    for (int j = 0; j < 16; ++j) { f32x4 z = {0.f, 0.f, 0.f, 0.f}; acc[i][j] = z; }

#define STAGE_J(bi, k0) { u16* bas = U + (bi) * 12288; \
    _Pragma("unroll") for (int j = 0; j < 2; ++j) { int rb = (j << 6) + (w << 4); \
      gload16(gated + (row0 + rb + gr) * 512 + (k0) + gcs, bas + rb * 32); } \
    _Pragma("unroll") for (int j = 0; j < 4; ++j) { int rb = (j << 6) + (w << 4); \
      gload16(wfpt + (col0 + rb + gr) * 512 + (k0) + gcs, bas + 4096 + rb * 32); } }

#define COMP_J(bi) { const u16* bas = U + (bi) * 12288; bf16x8 a[2]; \
    _Pragma("unroll") for (int rt = 0; rt < 2; ++rt) \
      a[rt] = *(const bf16x8*)&bas[((w << 5) + (rt << 4) + lr) * 32 + ca]; \
    _Pragma("unroll") for (int ct = 0; ct < 16; ++ct) { \
      bf16x8 bb = *(const bf16x8*)&bas[4096 + ((ct << 4) + lr) * 32 + ca]; \
      acc[0][ct] = __builtin_amdgcn_mfma_f32_16x16x32_bf16(a[0], bb, acc[0][ct], 0, 0, 0); \
      acc[1][ct] = __builtin_amdgcn_mfma_f32_16x16x32_bf16(a[1], bb, acc[1][ct], 0, 0, 0); } }

  STAGE_J(0, 0);
  STAGE_J(1, 32);
  #pragma unroll
  for (int tt = 0; tt < 16; ++tt) {
    if (tt < 15) asm volatile("s_waitcnt vmcnt(6)\n\ts_barrier" ::: "memory");
    else         asm volatile("s_waitcnt vmcnt(0)\n\ts_barrier" ::: "memory");
    if (tt < 14) STAGE_J((tt + 2) % 3, (tt + 2) * 32);
    COMP_J(tt % 3);
  }
#undef STAGE_J
#undef COMP_J
  // bias + row sum-of-squares
  float part[2][4] = {{0, 0, 0, 0}, {0, 0, 0, 0}};
  #pragma unroll
  for (int ct = 0; ct < 16; ++ct) {
    float bv = bfp[col0 + (ct << 4) + lr];
    #pragma unroll
    for (int rt = 0; rt < 2; ++rt)
      #pragma unroll
      for (int j = 0; j < 4; ++j) {
        acc[rt][ct][j] += bv;
        part[rt][j] += acc[rt][ct][j] * acc[rt][ct][j];
      }
  }
  #pragma unroll
  for (int m = 1; m <= 8; m <<= 1)
    #pragma unroll
    for (int rt = 0; rt < 2; ++rt)
      #pragma unroll
      for (int j = 0; j < 4; ++j)
        part[rt][j] += __shfl_xor(part[rt][j], m, 64);
  if (lr == 0) {
    #pragma unroll
    for (int rt = 0; rt < 2; ++rt)
      #pragma unroll
      for (int j = 0; j < 4; ++j)
        atomicAdd(&sumsq[row0 + (w << 5) + (rt << 4) + (lq << 2) + j], part[rt][j]);
  }
  __syncthreads();   // all waves done reading staging buffers
  // stage E cols [32 anchors][256 local cols] bf16 at U+17408 (stride 264)
  {
    int a = t >> 3, cb = (t & 7) << 5;
    const float* ep = E + a * 512 + col0 + cb;
    u16* dp = U + 17408 + a * 264 + cb;
    #pragma unroll
    for (int i = 0; i < 8; ++i) {
      float4 v = *(const float4*)(ep + (i << 2));
      s16x4 b;
      b[0] = (short)f2bf(v.x); b[1] = (short)f2bf(v.y);
      b[2] = (short)f2bf(v.z); b[3] = (short)f2bf(v.w);
      *(s16x4*)(dp + (i << 2)) = b;
    }
  }
  // S = y_tile @ E_cols^T, two 128-col halves through Yl[128][136]
  f32x4 acc2[2][2];
  #pragma unroll
  for (int i = 0; i < 2; ++i)
    #pragma unroll
    for (int j = 0; j < 2; ++j) { f32x4 z = {0.f, 0.f, 0.f, 0.f}; acc2[i][j] = z; }
  #pragma unroll
  for (int half = 0; half < 2; ++half) {
    if (half) __syncthreads();    // drain half-0 Yl reads before rewrite
    #pragma unroll
    for (int ct = 0; ct < 8; ++ct)
      #pragma unroll
      for (int rt = 0; rt < 2; ++rt)
        #pragma unroll
        for (int j = 0; j < 4; ++j) {
          int r = (w << 5) + (rt << 4) + (lq << 2) + j;
          U[r * 136 + (ct << 4) + lr] = f2bf(acc[rt][(half << 3) + ct][j]);
        }
    __syncthreads();
    #pragma unroll
    for (int ks = 0; ks < 4; ++ks) {
      bf16x8 a0 = *(const bf16x8*)&U[((w << 5) + lr) * 136 + (ks << 5) + (lq << 3)];
      bf16x8 a1 = *(const bf16x8*)&U[((w << 5) + 16 + lr) * 136 + (ks << 5) + (lq << 3)];
      bf16x8 b0 = *(const bf16x8*)&U[17408 + lr * 264 + (half << 7) + (ks << 5) + (lq << 3)];
      bf16x8 b1 = *(const bf16x8*)&U[17408 + (16 + lr) * 264 + (half << 7) + (ks << 5) + (lq << 3)];
      acc2[0][0] = __builtin_amdgcn_mfma_f32_16x16x32_bf16(a0, b0, acc2[0][0], 0, 0, 0);
      acc2[0][1] = __builtin_amdgcn_mfma_f32_16x16x32_bf16(a0, b1, acc2[0][1], 0, 0, 0);
      acc2[1][0] = __builtin_amdgcn_mfma_f32_16x16x32_bf16(a1, b0, acc2[1][0], 0, 0, 0);
      acc2[1][1] = __builtin_amdgcn_mfma_f32_16x16x32_bf16(a1, b1, acc2[1][1], 0, 0, 0);
    }
  }
  #pragma unroll
  for (int rt = 0; rt < 2; ++rt)
    #pragma unroll
    for (int c2 = 0; c2 < 2; ++c2)
      #pragma unroll
      for (int j = 0; j < 4; ++j) {
        int r = row0 + (w << 5) + (rt << 4) + (lq << 2) + j;
        int a = (c2 << 4) + lr;
        atomicAdd(&aff32[(r << 5) + a], acc2[rt][c2][j]);
      }
}

// ---------------- aff = softmax over 32 anchors (elementwise finish) ----------------
__global__ __launch_bounds__(256) void k_softmax(
    const float* __restrict__ aff32, const float* __restrict__ sumsq,
    const float* __restrict__ consts, u16* __restrict__ aff)
{
  const int t = threadIdx.x;
  const int lane = t & 63, wv = t >> 6;
  const int a = lane & 31, rh = lane >> 5;
  float ive = consts[CI_INVE + a], ab = consts[CI_ABIAS + a];
  #pragma unroll
  for (int it = 0; it < 4; ++it) {
    int r = (blockIdx.x << 5) + (wv << 3) + (it << 1) + rh;
    float invy = 1.0f / fmaxf(sqrtf(sumsq[r]), 1e-12f);
    float v = aff32[(r << 5) + a] * ive * invy + ab;
    float mx = v;
    #pragma unroll
    for (int m = 1; m <= 16; m <<= 1) mx = fmaxf(mx, __shfl_xor(mx, m, 64));
    float e = __expf(v - mx);
    float sm = e;
    #pragma unroll
    for (int m = 1; m <= 16; m <<= 1) sm += __shfl_xor(sm, m, 64);
    aff[(r << 5) + a] = f2bf(e * (1.0f / sm));
  }
}

// ---------------- out = gated + aff @ E  (f32 output!) ----------------
__global__ __launch_bounds__(256, 2) void k_out(
    const u16* __restrict__ gated, const u16* __restrict__ aff,
    const u16* __restrict__ et, float* __restrict__ out)
{
  __shared__ u16 ETl[512][40];
  __shared__ u16 Afl[64][40];
  __shared__ u16 Ol[64][520];
  const int row0 = blockIdx.x << 6;
  const int t = threadIdx.x;
  const int w = t >> 6, lane = t & 63, lr = lane & 15, lq = lane >> 4;
  {
    int r = t >> 2, k8 = (t & 3) << 3;
    *(bf16x8*)&Afl[r][k8] = *(const bf16x8*)(aff + (row0 + r) * 32 + k8);
  }
  #pragma unroll
  for (int i = 0; i < 8; ++i) {
    int s = (i << 8) + t;
    int d = s >> 2, k8 = (s & 3) << 3;
    *(bf16x8*)&ETl[d][k8] = *(const bf16x8*)(et + d * 32 + k8);
  }
  __syncthreads();
  bf16x8 a[4];
  #pragma unroll
  for (int rt = 0; rt < 4; ++rt)
    a[rt] = *(const bf16x8*)&Afl[(rt << 4) + lr][lq << 3];
  f32x4 z = {0.f, 0.f, 0.f, 0.f};
  #pragma unroll
  for (int ct = 0; ct < 8; ++ct) {
    bf16x8 bb = *(const bf16x8*)&ETl[(w << 7) + (ct << 4) + lr][lq << 3];
    #pragma unroll
    for (int rt = 0; rt < 4; ++rt) {
      f32x4 o = __builtin_amdgcn_mfma_f32_16x16x32_bf16(a[rt], bb, z, 0, 0, 0);
      #pragma unroll
      for (int j = 0; j < 4; ++j)
        Ol[(rt << 4) + (lq << 2) + j][(w << 7) + (ct << 4) + lr] = f2bf(o[j]);
    }
  }
  __syncthreads();
  // out = f32(gated + anchor), float4 stores
  #pragma unroll
  for (int it = 0; it < 32; ++it) {
    int s = (it << 8) + t;
    int r = s >> 7, c4 = (s & 127) << 2;
    s16x4 g4 = *(const s16x4*)(gated + (row0 + r) * 512 + c4);
    s16x4 a4 = *(const s16x4*)(&Ol[0][0] + r * 520 + c4);
    float4 o;
    o.x = bf2f((u16)g4[0]) + bf2f((u16)a4[0]);
    o.y = bf2f((u16)g4[1]) + bf2f((u16)a4[1]);
    o.z = bf2f((u16)g4[2]) + bf2f((u16)a4[2]);
    o.w = bf2f((u16)g4[3]) + bf2f((u16)a4[3]);
    *(float4*)(out + (row0 + r) * 512 + c4) = o;
  }
}

extern "C" void kernel_launch(void* const* d_in, const int* in_sizes, int n_in,
                              void* d_out, int out_size, void* d_ws, size_t ws_size,
                              hipStream_t stream) {
  (void)in_sizes; (void)n_in; (void)out_size;
  if (ws_size < WS_NEEDED) return;
  const float* feat = (const float*)d_in[0];
  const float* sfp  = (const float*)d_in[1];
  const float* tfp  = (const float*)d_in[2];
  const float* wf1  = (const float*)d_in[3];
  const float* bf1  = (const float*)d_in[4];
  const float* wf2  = (const float*)d_in[5];
  const float* wc   = (const float*)d_in[7];
  const float* bc   = (const float*)d_in[8];
  const float* wg1  = (const float*)d_in[9];
  const float* bg1  = (const float*)d_in[10];
  const float* wg2  = (const float*)d_in[11];
  const float* bg2  = (const float*)d_in[12];
  const float* E    = (const float*)d_in[13];
  const float* wfp  = (const float*)d_in[14];
  const float* bfp  = (const float*)d_in[15];
  const float* wfq  = (const float*)d_in[16];
  const float* bfq  = (const float*)d_in[17];

  char* ws = (char*)d_ws;
  float* grad   = (float*)(ws + OFF_GRAD);
  float* sumsq  = (float*)(ws + OFF_SUMSQ);
  float* consts = (float*)(ws + OFF_CONSTS);
  u16* ws16  = (u16*)ws;
  u16* wf1t  = (u16*)(ws + OFF_WF1T);
  u16* wg2t  = (u16*)(ws + OFF_WG2T);
  u16* wfpt  = (u16*)(ws + OFF_WFPT);
  u16* et    = (u16*)(ws + OFF_ET);
  u16* aff   = (u16*)(ws + OFF_AFF);
  u16* gated = (u16*)(ws + OFF_GATED);
  float* aff32 = (float*)d_out;                  // 8 MB partial scores: first part of d_out
  u16* featbf  = (u16*)d_out + 33554432;         // bf16 feat: second half of d_out
  float* out = (float*)d_out;

  hipMemsetAsync(ws + OFF_SUMSQ, 0, 262144, stream);
  hipMemsetAsync(d_out, 0, 8388608, stream);     // zero aff32 accumulators
  k_cvt<<<dim3(16384), dim3(256), 0, stream>>>(feat, featbf);
  k_pre<<<dim3(10), dim3(256), 0, stream>>>(sfp, tfp, wf1, bf1, wc, bc, wg1, bg1, wfq, bfq, E, consts);
  k_transpose<<<dim3(912), dim3(256), 0, stream>>>(wf1, wg2, wfp, E, ws16);
  k_potential<<<dim3(2048), dim3(256), 0, stream>>>(featbf, wf1t, wf2, consts, grad);
  k_gate<<<dim3(2048), dim3(256), 0, stream>>>(featbf, grad, wg1, wg2t, bg2, consts, gated);
  k_proj<<<dim3(1024), dim3(256), 0, stream>>>(gated, wfpt, bfp, E, aff32, sumsq);
  k_softmax<<<dim3(2048), dim3(256), 0, stream>>>(aff32, sumsq, consts, aff);
  k_out<<<dim3(1024), dim3(256), 0, stream>>>(gated, aff, et, out);
}